// Round 1
// baseline (555.393 us; speedup 1.0000x reference)
//
#include <hip/hip_runtime.h>

// Problem constants (from setup_inputs): masks [N=100, H=800, W=1280] fp32.
#define N_MASKS 100
#define H 800
#define W 1280
#define ROWS_PER_BLOCK 8
#define BLOCKS_PER_MASK (H / ROWS_PER_BLOCK)     // 100
#define F4_PER_ROW (W / 4)                       // 320
#define F4_PER_BLOCK (ROWS_PER_BLOCK * F4_PER_ROW) // 2560
#define THREADS 256
#define F4_PER_THREAD (F4_PER_BLOCK / THREADS)   // 10

// ws layout: int ws[N][4] = {xmin, ymin, xmax, ymax}
__global__ void bg_init(int* __restrict__ ws) {
    int i = blockIdx.x * blockDim.x + threadIdx.x;
    if (i < N_MASKS * 4) {
        int k = i & 3;
        ws[i] = (k == 0) ? W : (k == 1) ? H : -1;  // sentinels match jnp.where fallback
    }
}

__global__ __launch_bounds__(THREADS) void bg_reduce(const float4* __restrict__ masks,
                                                     int* __restrict__ ws) {
    const int mask = blockIdx.y;
    const int rowBase = blockIdx.x * ROWS_PER_BLOCK;
    const float4* base = masks + (size_t)mask * (H * F4_PER_ROW)
                               + (size_t)rowBase * F4_PER_ROW;

    int xmin = W, xmax = -1, ymin = H, ymax = -1;

    const int t = threadIdx.x;
#pragma unroll
    for (int k = 0; k < F4_PER_THREAD; ++k) {
        int i = t + k * THREADS;            // f4 index within 8-row chunk; coalesced
        int row = i / F4_PER_ROW;           // const divide -> magic mul
        int c4  = i - row * F4_PER_ROW;
        float4 v = base[i];
        unsigned m = (unsigned)(v.x > 0.5f)
                   | ((unsigned)(v.y > 0.5f) << 1)
                   | ((unsigned)(v.z > 0.5f) << 2)
                   | ((unsigned)(v.w > 0.5f) << 3);
        if (m) {
            int xb = c4 * 4;
            int y = rowBase + row;
            xmin = min(xmin, xb + (__ffs(m) - 1));
            xmax = max(xmax, xb + (31 - __clz(m)));
            ymin = min(ymin, y);
            ymax = max(ymax, y);
        }
    }

    // wave (64-lane) shuffle reduction
#pragma unroll
    for (int off = 32; off > 0; off >>= 1) {
        xmin = min(xmin, __shfl_down(xmin, off, 64));
        xmax = max(xmax, __shfl_down(xmax, off, 64));
        ymin = min(ymin, __shfl_down(ymin, off, 64));
        ymax = max(ymax, __shfl_down(ymax, off, 64));
    }

    __shared__ int s[4][4];  // 4 waves x {xmin,xmax,ymin,ymax}
    const int wave = t >> 6;
    const int lane = t & 63;
    if (lane == 0) {
        s[wave][0] = xmin; s[wave][1] = xmax; s[wave][2] = ymin; s[wave][3] = ymax;
    }
    __syncthreads();
    if (t == 0) {
        xmin = min(min(s[0][0], s[1][0]), min(s[2][0], s[3][0]));
        xmax = max(max(s[0][1], s[1][1]), max(s[2][1], s[3][1]));
        ymin = min(min(s[0][2], s[1][2]), min(s[2][2], s[3][2]));
        ymax = max(max(s[0][3], s[1][3]), max(s[2][3], s[3][3]));
        int* w = ws + mask * 4;
        atomicMin(&w[0], xmin);   // device-scope by default on CDNA
        atomicMin(&w[1], ymin);
        atomicMax(&w[2], xmax);
        atomicMax(&w[3], ymax);
    }
}

__global__ void bg_finalize(const int* __restrict__ ws, float* __restrict__ out) {
    int i = blockIdx.x * blockDim.x + threadIdx.x;
    if (i < N_MASKS * 4) out[i] = (float)ws[i];
}

extern "C" void kernel_launch(void* const* d_in, const int* in_sizes, int n_in,
                              void* d_out, int out_size, void* d_ws, size_t ws_size,
                              hipStream_t stream) {
    const float* masks = (const float*)d_in[0];
    float* out = (float*)d_out;
    int* ws = (int*)d_ws;  // re-poisoned to 0xAA before every call -> bg_init re-seeds

    bg_init<<<dim3((N_MASKS * 4 + 255) / 256), dim3(256), 0, stream>>>(ws);

    dim3 grid(BLOCKS_PER_MASK, N_MASKS);  // 100 x 100 = 10,000 blocks (~39/CU)
    bg_reduce<<<grid, dim3(THREADS), 0, stream>>>((const float4*)masks, ws);

    bg_finalize<<<dim3((N_MASKS * 4 + 255) / 256), dim3(256), 0, stream>>>(ws, out);
}

// Round 2
// 482.876 us; speedup vs baseline: 1.1502x; 1.1502x over previous
//
#include <hip/hip_runtime.h>

// masks [N=100, H=800, W=1280] fp32; out = per-mask [xmin,ymin,xmax,ymax] as float.
#define N_MASKS 100
#define H 800
#define W 1280
#define ROWS_PER_BLOCK 8
#define CHUNKS (H / ROWS_PER_BLOCK)                 // 100 chunks per mask
#define F4_PER_ROW (W / 4)                          // 320
#define F4_PER_BLOCK (ROWS_PER_BLOCK * F4_PER_ROW)  // 2560
#define THREADS 256
#define F4_PER_THREAD (F4_PER_BLOCK / THREADS)      // 10
#define N_PRIORITY (2 * N_MASKS)                    // 200 priority blocks
#define BULK_PER_MASK (CHUNKS - 2)                  // 98

// ws layout: int ws[N][4] = {xmin, ymin, xmax, ymax}
__global__ void bg_init(int* __restrict__ ws) {
    int i = blockIdx.x * blockDim.x + threadIdx.x;
    if (i < N_MASKS * 4) {
        int k = i & 3;
        ws[i] = (k == 0) ? W : (k == 1) ? H : -1;  // sentinels match jnp.where fallback
    }
}

__global__ __launch_bounds__(THREADS) void bg_reduce(const float4* __restrict__ masks,
                                                     int* __restrict__ ws) {
    // Block remap: first 200 blocks = top/bottom chunk of every mask ("priority",
    // establish the bbox); remaining 9800 = middle chunks ("bulk", may skip).
    const int j = blockIdx.x;
    int mask, chunk;
    bool bulk;
    if (j < N_PRIORITY) {
        mask = j >> 1;
        chunk = (j & 1) ? (CHUNKS - 1) : 0;
        bulk = false;
    } else {
        int idx = j - N_PRIORITY;
        mask = idx / BULK_PER_MASK;                 // magic-mul
        chunk = 1 + (idx - mask * BULK_PER_MASK);
        bulk = true;
    }
    const int rowBase = chunk * ROWS_PER_BLOCK;
    int* w = ws + mask * 4;

    // Early-exit: monotone atomics mean the global box only tightens, so if it
    // already covers everything this block could contribute, skip the scan.
    // Stale reads (cross-XCD) => no skip => still correct, just slower.
    __shared__ int skip;
    if (bulk) {
        if (threadIdx.x == 0) {
            int gxmin = __hip_atomic_load(&w[0], __ATOMIC_RELAXED, __HIP_MEMORY_SCOPE_AGENT);
            int gymin = __hip_atomic_load(&w[1], __ATOMIC_RELAXED, __HIP_MEMORY_SCOPE_AGENT);
            int gxmax = __hip_atomic_load(&w[2], __ATOMIC_RELAXED, __HIP_MEMORY_SCOPE_AGENT);
            int gymax = __hip_atomic_load(&w[3], __ATOMIC_RELAXED, __HIP_MEMORY_SCOPE_AGENT);
            skip = (gxmin == 0) & (gxmax == (W - 1)) &
                   (gymin <= rowBase) & (gymax >= rowBase + ROWS_PER_BLOCK - 1);
        }
        __syncthreads();
        if (skip) return;
    }

    const float4* base = masks + (size_t)mask * (H * F4_PER_ROW)
                               + (size_t)rowBase * F4_PER_ROW;

    int xmin = W, xmax = -1, ymin = H, ymax = -1;
    const int t = threadIdx.x;
#pragma unroll
    for (int k = 0; k < F4_PER_THREAD; ++k) {
        int i = t + k * THREADS;            // coalesced float4 stream
        int row = i / F4_PER_ROW;
        int c4  = i - row * F4_PER_ROW;
        float4 v = base[i];
        unsigned m = (unsigned)(v.x > 0.5f)
                   | ((unsigned)(v.y > 0.5f) << 1)
                   | ((unsigned)(v.z > 0.5f) << 2)
                   | ((unsigned)(v.w > 0.5f) << 3);
        if (m) {
            int xb = c4 * 4;
            int y = rowBase + row;
            xmin = min(xmin, xb + (__ffs(m) - 1));
            xmax = max(xmax, xb + (31 - __clz(m)));
            ymin = min(ymin, y);
            ymax = max(ymax, y);
        }
    }

    // 64-lane wave shuffle reduction
#pragma unroll
    for (int off = 32; off > 0; off >>= 1) {
        xmin = min(xmin, __shfl_down(xmin, off, 64));
        xmax = max(xmax, __shfl_down(xmax, off, 64));
        ymin = min(ymin, __shfl_down(ymin, off, 64));
        ymax = max(ymax, __shfl_down(ymax, off, 64));
    }

    __shared__ int s[4][4];
    const int wave = t >> 6;
    const int lane = t & 63;
    if (lane == 0) {
        s[wave][0] = xmin; s[wave][1] = xmax; s[wave][2] = ymin; s[wave][3] = ymax;
    }
    __syncthreads();
    if (t == 0) {
        xmin = min(min(s[0][0], s[1][0]), min(s[2][0], s[3][0]));
        xmax = max(max(s[0][1], s[1][1]), max(s[2][1], s[3][1]));
        ymin = min(min(s[0][2], s[1][2]), min(s[2][2], s[3][2]));
        ymax = max(max(s[0][3], s[1][3]), max(s[2][3], s[3][3]));
        atomicMin(&w[0], xmin);
        atomicMin(&w[1], ymin);
        atomicMax(&w[2], xmax);
        atomicMax(&w[3], ymax);
    }
}

__global__ void bg_finalize(const int* __restrict__ ws, float* __restrict__ out) {
    int i = blockIdx.x * blockDim.x + threadIdx.x;
    if (i < N_MASKS * 4) out[i] = (float)ws[i];
}

extern "C" void kernel_launch(void* const* d_in, const int* in_sizes, int n_in,
                              void* d_out, int out_size, void* d_ws, size_t ws_size,
                              hipStream_t stream) {
    const float* masks = (const float*)d_in[0];
    float* out = (float*)d_out;
    int* ws = (int*)d_ws;

    bg_init<<<dim3(1), dim3(512), 0, stream>>>(ws);

    // Linear grid: priority blocks (0..199) dispatch first, bulk after.
    dim3 grid(N_PRIORITY + N_MASKS * BULK_PER_MASK);  // 200 + 9800 = 10000
    bg_reduce<<<grid, dim3(THREADS), 0, stream>>>((const float4*)masks, ws);

    bg_finalize<<<dim3(1), dim3(512), 0, stream>>>(ws, out);
}